// Round 9
// baseline (595.215 us; speedup 1.0000x reference)
//
#include <hip/hip_runtime.h>
#include <hip/hip_bf16.h>

typedef __bf16 bf16_t;
typedef __bf16 bf16x8 __attribute__((ext_vector_type(8)));
typedef float f32x4 __attribute__((ext_vector_type(4)));

#define MFMA16(a, b, c) __builtin_amdgcn_mfma_f32_16x16x32_bf16(a, b, c, 0, 0, 0)

// Load 8 consecutive elements as bf16x8, converting from f32 if needed.
template <typename T>
__device__ __forceinline__ bf16x8 load8(const T* p);
template <>
__device__ __forceinline__ bf16x8 load8<bf16_t>(const bf16_t* p) {
  return *(const bf16x8*)p;
}
template <>
__device__ __forceinline__ bf16x8 load8<float>(const float* p) {
  f32x4 a = *(const f32x4*)p;
  f32x4 b = *(const f32x4*)(p + 4);
  bf16x8 r;
#pragma unroll
  for (int e = 0; e < 4; ++e) {
    r[e] = (bf16_t)a[e];
    r[4 + e] = (bf16_t)b[e];
  }
  return r;
}

// ---------------------------------------------------------------------------
// GEMM: C[m][n] = sum_k A[m][k] * W[n][k]  (+ bias[n]).  f32 accumulate.
// A: [M,K] elem TA, row stride lda. W: [N,K] elem TW (B^T form).
// C: elem TC (f32 or bf16), row stride ldc.
// 128x128 tile, 4 waves (2x2), 64x64 per wave, BK=32.
// Compute path verified on device (R5 == R6 bit-identity vs scalar GEMM).
// ---------------------------------------------------------------------------
template <typename TA, typename TW, typename TC, bool BIAS>
__global__ __launch_bounds__(256, 2) void gemm_bt(
    const TA* __restrict__ A, int lda, const TW* __restrict__ W,
    const float* __restrict__ bias, TC* __restrict__ C, int ldc,
    int M, int N, int K) {
  __shared__ bf16_t As[128 * 40];  // +8 pad: 2-way bank aliasing (free)
  __shared__ bf16_t Bs[128 * 40];

  const int tid = threadIdx.x;
  const int lane = tid & 63;
  const int wave = tid >> 6;
  const int l16 = lane & 15;
  const int quad = lane >> 4;
  const int wm = wave & 1;
  const int wn = wave >> 1;
  const int m0 = blockIdx.y * 128;
  const int n0 = blockIdx.x * 128;

  const int srow = tid >> 1;
  const int scol = (tid & 1) * 16;
  const TA* Ag = A + (size_t)(m0 + srow) * lda + scol;
  const TW* Wg = W + (size_t)(n0 + srow) * K + scol;
  bf16_t* Asw = &As[srow * 40 + scol];
  bf16_t* Bsw = &Bs[srow * 40 + scol];

  f32x4 acc[4][4] = {};

  for (int k0 = 0; k0 < K; k0 += 32) {
    __syncthreads();
    *(bf16x8*)(Asw) = load8<TA>(Ag + k0);
    *(bf16x8*)(Asw + 8) = load8<TA>(Ag + k0 + 8);
    *(bf16x8*)(Bsw) = load8<TW>(Wg + k0);
    *(bf16x8*)(Bsw + 8) = load8<TW>(Wg + k0 + 8);
    __syncthreads();

    bf16x8 af[4], bfr[4];
#pragma unroll
    for (int i = 0; i < 4; ++i) {
      af[i] = *(const bf16x8*)&As[(wm * 64 + i * 16 + l16) * 40 + quad * 8];
      bfr[i] = *(const bf16x8*)&Bs[(wn * 64 + i * 16 + l16) * 40 + quad * 8];
    }
#pragma unroll
    for (int mi = 0; mi < 4; ++mi)
#pragma unroll
      for (int ni = 0; ni < 4; ++ni)
        acc[mi][ni] = MFMA16(af[mi], bfr[ni], acc[mi][ni]);
  }

#pragma unroll
  for (int ni = 0; ni < 4; ++ni) {
    const int col = n0 + wn * 64 + ni * 16 + l16;
    const float bv = BIAS ? bias[col] : 0.0f;
#pragma unroll
    for (int mi = 0; mi < 4; ++mi) {
      const int row = m0 + wm * 64 + mi * 16 + quad * 4;
#pragma unroll
      for (int r = 0; r < 4; ++r)
        C[(size_t)(row + r) * ldc + col] = (TC)(acc[mi][ni][r] + bv);
    }
  }
}

// ---------------------------------------------------------------------------
// Flash attention (causal), MFMA. Dense Q/K/V arrays, each [B*T, C] bf16,
// head h at cols h*64..+63. Output overwrites Q in place (each block reads
// its own Q tile into registers at start; Q regions disjoint across blocks;
// K/V never written). grid = (T/64, B*H), block 256 = 4 waves; wave w owns
// q rows q0+w*16..+15. Online softmax; P round-trips LDS (C->A layout).
// Compute path verified on device (R3 == R4 bit-identity vs scalar attn).
// ---------------------------------------------------------------------------
__global__ __launch_bounds__(256, 2) void attn_mfma(
    bf16_t* __restrict__ Q, const bf16_t* __restrict__ K,
    const bf16_t* __restrict__ V) {
  constexpr int T = 2048, C = 1024;

  __shared__ bf16_t Ks[64 * 72];       // K tile  [token][d], +8 pad
  __shared__ bf16_t Vt[64 * 72];       // V tile transposed [d][token], +8 pad
  __shared__ bf16_t Ps[4 * 16 * 72];   // per-wave P tile [qrow][token]

  const int tid = threadIdx.x;
  const int lane = tid & 63;
  const int wave = tid >> 6;
  const int l16 = lane & 15;
  const int quad = lane >> 4;
  const int qt = blockIdx.x;
  const int b = blockIdx.y >> 4;
  const int h = blockIdx.y & 15;
  const int q0 = qt * 64;
  const size_t rb = (size_t)b * T;

  bf16x8 qf[2];
  {
    const int t = q0 + wave * 16 + l16;
    const bf16_t* qp = Q + (rb + t) * C + h * 64 + quad * 8;
    qf[0] = *(const bf16x8*)(qp);
    qf[1] = *(const bf16x8*)(qp + 32);
  }

  f32x4 Of[4] = {};
  float mrow[4] = {-1e30f, -1e30f, -1e30f, -1e30f};
  float lrow[4] = {0.f, 0.f, 0.f, 0.f};

  const int stok = tid >> 2;        // 0..63
  const int sd = (tid & 3) * 16;    // 0,16,32,48

  for (int j0 = 0; j0 <= q0; j0 += 64) {
    __syncthreads();
    {
      const bf16_t* kp = K + (rb + j0 + stok) * C + h * 64 + sd;
      *(bf16x8*)&Ks[stok * 72 + sd] = *(const bf16x8*)(kp);
      *(bf16x8*)&Ks[stok * 72 + sd + 8] = *(const bf16x8*)(kp + 8);
      const bf16_t* vp = V + (rb + j0 + stok) * C + h * 64 + sd;
      bf16x8 v0 = *(const bf16x8*)(vp);
      bf16x8 v1 = *(const bf16x8*)(vp + 8);
#pragma unroll
      for (int e = 0; e < 8; ++e) {
        Vt[(sd + e) * 72 + stok] = v0[e];
        Vt[(sd + 8 + e) * 72 + stok] = v1[e];
      }
    }
    __syncthreads();

    float Sv[4][4];
    const int qrow = q0 + wave * 16 + quad * 4;
#pragma unroll
    for (int nt = 0; nt < 4; ++nt) {
      f32x4 s = {};
#pragma unroll
      for (int s2 = 0; s2 < 2; ++s2) {
        bf16x8 kf =
            *(const bf16x8*)&Ks[(nt * 16 + l16) * 72 + s2 * 32 + quad * 8];
        s = MFMA16(qf[s2], kf, s);
      }
      const int key = j0 + nt * 16 + l16;
#pragma unroll
      for (int r = 0; r < 4; ++r) {
        float v = s[r] * 0.125f;  // 1/sqrt(64)
        Sv[nt][r] = (key > qrow + r) ? -1e30f : v;
      }
    }

    float alpha[4], mnew[4];
#pragma unroll
    for (int r = 0; r < 4; ++r) {
      float v = fmaxf(fmaxf(Sv[0][r], Sv[1][r]), fmaxf(Sv[2][r], Sv[3][r]));
#pragma unroll
      for (int off = 1; off < 16; off <<= 1)
        v = fmaxf(v, __shfl_xor(v, off, 16));
      mnew[r] = fmaxf(mrow[r], v);
      alpha[r] = __expf(mrow[r] - mnew[r]);
      mrow[r] = mnew[r];
    }
#pragma unroll
    for (int r = 0; r < 4; ++r) {
      float rs = 0.f;
#pragma unroll
      for (int nt = 0; nt < 4; ++nt) {
        float p = __expf(Sv[nt][r] - mnew[r]);
        Sv[nt][r] = p;
        rs += p;
      }
#pragma unroll
      for (int off = 1; off < 16; off <<= 1) rs += __shfl_xor(rs, off, 16);
      lrow[r] = lrow[r] * alpha[r] + rs;
    }
#pragma unroll
    for (int dt = 0; dt < 4; ++dt)
#pragma unroll
      for (int r = 0; r < 4; ++r) Of[dt][r] *= alpha[r];

    bf16_t* pw = &Ps[wave * 16 * 72];
#pragma unroll
    for (int nt = 0; nt < 4; ++nt)
#pragma unroll
      for (int r = 0; r < 4; ++r)
        pw[(quad * 4 + r) * 72 + nt * 16 + l16] = (bf16_t)Sv[nt][r];

    __syncthreads();

    bf16x8 pf[2];
    pf[0] = *(const bf16x8*)&pw[l16 * 72 + quad * 8];
    pf[1] = *(const bf16x8*)&pw[l16 * 72 + 32 + quad * 8];
#pragma unroll
    for (int dt = 0; dt < 4; ++dt) {
#pragma unroll
      for (int s2 = 0; s2 < 2; ++s2) {
        bf16x8 vf =
            *(const bf16x8*)&Vt[(dt * 16 + l16) * 72 + s2 * 32 + quad * 8];
        Of[dt] = MFMA16(pf[s2], vf, Of[dt]);
      }
    }
  }

  const int t = q0 + wave * 16 + quad * 4;
#pragma unroll
  for (int r = 0; r < 4; ++r) {
    const float inv = 1.0f / lrow[r];
    bf16_t* op = Q + (rb + t + r) * C + h * 64 + l16;
#pragma unroll
    for (int dt = 0; dt < 4; ++dt) op[dt * 16] = (bf16_t)(Of[dt][r] * inv);
  }
}

// ---------------------------------------------------------------------------
// Measured I/O contract (R8 probe): ALL inputs f32; output read as f32.
// ---------------------------------------------------------------------------
extern "C" void kernel_launch(void* const* d_in, const int* in_sizes, int n_in,
                              void* d_out, int out_size, void* d_ws,
                              size_t ws_size, hipStream_t stream) {
  constexpr int B = 4, T = 2048, C = 1024;
  constexpr int M = B * T;  // 8192

  // Bind inputs BY SIZE (element counts pairwise distinct).
  const float* x = (const float*)d_in[0];
  const float* w_qkv = (const float*)d_in[1];
  const float* w_out = (const float*)d_in[2];
  const float* b_out = (const float*)d_in[3];
  for (int i = 0; i < n_in; ++i) {
    const long long s = in_sizes[i];
    if (s == (long long)M * C) x = (const float*)d_in[i];
    else if (s == (long long)3 * C * C) w_qkv = (const float*)d_in[i];
    else if (s == (long long)C * C) w_out = (const float*)d_in[i];
    else if (s == C) b_out = (const float*)d_in[i];
  }

  float* outp = (float*)d_out;  // f32 output

  // Workspace: 48 MB. Q | K | V, each [M, C] bf16 (16 MB). (48 MB proven
  // safe in R3/R4.)
  bf16_t* Qbuf = (bf16_t*)d_ws;
  bf16_t* Kbuf = Qbuf + (size_t)M * C;
  bf16_t* Vbuf = Kbuf + (size_t)M * C;

  const dim3 g1(C / 128, M / 128);  // (8, 64)

  // Q/K/V projections (f32 inputs -> bf16 staging -> MFMA -> bf16 out).
  gemm_bt<float, float, bf16_t, false><<<g1, 256, 0, stream>>>(
      x, C, w_qkv, nullptr, Qbuf, C, M, C, C);
  gemm_bt<float, float, bf16_t, false><<<g1, 256, 0, stream>>>(
      x, C, w_qkv + (size_t)C * C, nullptr, Kbuf, C, M, C, C);
  gemm_bt<float, float, bf16_t, false><<<g1, 256, 0, stream>>>(
      x, C, w_qkv + (size_t)2 * C * C, nullptr, Vbuf, C, M, C, C);

  // attention; overwrites Qbuf in place
  attn_mfma<<<dim3(T / 64, B * 16), 256, 0, stream>>>(Qbuf, Kbuf, Vbuf);

  // out = att @ w_out^T + b_out  -> f32 directly into d_out
  gemm_bt<bf16_t, float, float, true><<<g1, 256, 0, stream>>>(
      Qbuf, C, w_out, b_out, outp, C, M, C, C);
}

// Round 10
// 433.635 us; speedup vs baseline: 1.3726x; 1.3726x over previous
//
#include <hip/hip_runtime.h>
#include <hip/hip_bf16.h>

typedef __bf16 bf16_t;
typedef __bf16 bf16x8 __attribute__((ext_vector_type(8)));
typedef float f32x4 __attribute__((ext_vector_type(4)));

#define MFMA16(a, b, c) __builtin_amdgcn_mfma_f32_16x16x32_bf16(a, b, c, 0, 0, 0)

// async 16B global->LDS (m97 pattern). lds ptr must be wave-uniform;
// HW writes lane's 16B to ldsbase + lane*16.
__device__ __forceinline__ void gld16(const bf16_t* g, bf16_t* l) {
  __builtin_amdgcn_global_load_lds(
      (const __attribute__((address_space(1))) unsigned int*)(const void*)g,
      (__attribute__((address_space(3))) unsigned int*)(void*)l, 16, 0, 0);
}

// ---------------------------------------------------------------------------
// f32 -> bf16 elementwise convert (n multiple of 8)
// ---------------------------------------------------------------------------
__global__ __launch_bounds__(256) void cvt_f32_bf16(
    const float* __restrict__ src, bf16_t* __restrict__ dst, long long n) {
  long long i = ((long long)blockIdx.x * 256 + threadIdx.x) * 8;
  const long long stride = (long long)gridDim.x * 256 * 8;
  for (; i < n; i += stride) {
    f32x4 a = *(const f32x4*)(src + i);
    f32x4 b = *(const f32x4*)(src + i + 4);
    bf16x8 r;
#pragma unroll
    for (int e = 0; e < 4; ++e) {
      r[e] = (bf16_t)a[e];
      r[4 + e] = (bf16_t)b[e];
    }
    *(bf16x8*)(dst + i) = r;
  }
}

// ---------------------------------------------------------------------------
// GEMM: C[m][n] = sum_k A[m][k]*W[n][k] (+bias). A bf16 via global_load_lds.
// W: bf16 via global_load_lds (WF32=false) or f32 via cvt staging (true).
// 128x128 tile, 4 waves (2x2), 64x64/wave, BK=32. Layouts R5==R6 verified.
// ---------------------------------------------------------------------------
template <bool WF32, typename TC, bool BIAS>
__global__ __launch_bounds__(256, 2) void gemm_async(
    const bf16_t* __restrict__ A, int lda, const void* __restrict__ Wv,
    const float* __restrict__ bias, TC* __restrict__ C, int ldc,
    int M, int N, int K) {
  constexpr int BST = WF32 ? 40 : 32;
  __shared__ bf16_t As[128 * 32];   // unpadded: global_load_lds layout
  __shared__ bf16_t Bs[128 * BST];

  const int tid = threadIdx.x;
  const int i = tid & 63;
  const int w = tid >> 6;
  const int l16 = tid & 15;
  const int quad = (tid >> 4) & 3;
  const int wm = w & 1;
  const int wn = w >> 1;
  const int m0 = blockIdx.y * 128;
  const int n0 = blockIdx.x * 128;

  // A async staging: wave w covers rows w*32..+31 in 2 calls of 16 rows.
  const bf16_t* ag = A + (size_t)(m0 + w * 32 + (i >> 2)) * lda + (i & 3) * 8;
  bf16_t* as0 = &As[(w * 32) * 32];
  bf16_t* as1 = &As[(w * 32 + 16) * 32];

  // B staging pointers
  const bf16_t* bg = nullptr;
  bf16_t *bs0 = nullptr, *bs1 = nullptr;
  const float* wfg = nullptr;
  bf16_t* bsw = nullptr;
  if (!WF32) {
    bg = (const bf16_t*)Wv + (size_t)(n0 + w * 32 + (i >> 2)) * K + (i & 3) * 8;
    bs0 = &Bs[(w * 32) * 32];
    bs1 = &Bs[(w * 32 + 16) * 32];
  } else {
    const int srow = tid >> 1;
    const int scol = (tid & 1) * 16;
    wfg = (const float*)Wv + (size_t)(n0 + srow) * K + scol;
    bsw = &Bs[srow * BST + scol];
  }

  f32x4 acc[4][4] = {};

  for (int k0 = 0; k0 < K; k0 += 32) {
    __syncthreads();
    gld16(ag + k0, as0);
    gld16(ag + 16 * lda + k0, as1);
    if (!WF32) {
      gld16(bg + k0, bs0);
      gld16(bg + 16 * K + k0, bs1);
    } else {
      f32x4 a = *(const f32x4*)(wfg + k0);
      f32x4 b = *(const f32x4*)(wfg + k0 + 4);
      f32x4 c2 = *(const f32x4*)(wfg + k0 + 8);
      f32x4 d = *(const f32x4*)(wfg + k0 + 12);
      bf16x8 r0, r1;
#pragma unroll
      for (int e = 0; e < 4; ++e) {
        r0[e] = (bf16_t)a[e];
        r0[4 + e] = (bf16_t)b[e];
        r1[e] = (bf16_t)c2[e];
        r1[4 + e] = (bf16_t)d[e];
      }
      *(bf16x8*)(bsw) = r0;
      *(bf16x8*)(bsw + 8) = r1;
    }
    __syncthreads();  // compiler drains vmcnt before s_barrier (m97)

    bf16x8 af[4], bfr[4];
#pragma unroll
    for (int t = 0; t < 4; ++t) {
      af[t] = *(const bf16x8*)&As[(wm * 64 + t * 16 + l16) * 32 + quad * 8];
      bfr[t] = *(const bf16x8*)&Bs[(wn * 64 + t * 16 + l16) * BST + quad * 8];
    }
#pragma unroll
    for (int mi = 0; mi < 4; ++mi)
#pragma unroll
      for (int ni = 0; ni < 4; ++ni)
        acc[mi][ni] = MFMA16(af[mi], bfr[ni], acc[mi][ni]);
  }

#pragma unroll
  for (int ni = 0; ni < 4; ++ni) {
    const int col = n0 + wn * 64 + ni * 16 + l16;
    const float bv = BIAS ? bias[col] : 0.0f;
#pragma unroll
    for (int mi = 0; mi < 4; ++mi) {
      const int row = m0 + wm * 64 + mi * 16 + quad * 4;
#pragma unroll
      for (int r = 0; r < 4; ++r)
        C[(size_t)(row + r) * ldc + col] = (TC)(acc[mi][ni][r] + bv);
    }
  }
}

// ---------------------------------------------------------------------------
// Flash attention (causal), qkv interleaved [B*T, 3C] bf16 (q|k|v).
// Output overwrites the Q slot in place (R3-verified disjointness).
// BM=128 q-rows/block: 4 waves x 2 m-tiles of 16 rows. BN=64 keys/tile.
// 2 barriers/tile (Ps round-trip is wave-private -> no barrier needed).
// Q pre-scaled by 1/8 (exact in bf16). Layouts R3==R4 verified.
// ---------------------------------------------------------------------------
__global__ __launch_bounds__(256, 4) void attn_mfma(bf16_t* __restrict__ qkv) {
  constexpr int T = 2048, C3 = 3072, C = 1024;
  __shared__ bf16_t Ks[64 * 72];      // [token][d], +8 pad
  __shared__ bf16_t Vt[64 * 72];      // [d][token], +8 pad
  __shared__ bf16_t Ps[4 * 16 * 72];  // per-wave P tile

  const int tid = threadIdx.x;
  const int wave = tid >> 6;
  const int l16 = tid & 15;
  const int quad = (tid >> 4) & 3;
  const int qt = blockIdx.x;
  const int b = blockIdx.y >> 4;
  const int h = blockIdx.y & 15;
  const int Q0 = qt * 128;
  bf16_t* base = qkv + (size_t)b * T * C3;

  // Q fragments, prescaled by 0.125 (power of 2: exact)
  bf16x8 qf[2][2];
#pragma unroll
  for (int mt = 0; mt < 2; ++mt) {
    const int t = Q0 + wave * 32 + mt * 16 + l16;
    const bf16_t* qp = base + (size_t)t * C3 + h * 64 + quad * 8;
    bf16x8 a = *(const bf16x8*)qp;
    bf16x8 c = *(const bf16x8*)(qp + 32);
#pragma unroll
    for (int e = 0; e < 8; ++e) {
      a[e] = (bf16_t)((float)a[e] * 0.125f);
      c[e] = (bf16_t)((float)c[e] * 0.125f);
    }
    qf[mt][0] = a;
    qf[mt][1] = c;
  }

  f32x4 Of[2][4] = {};
  float mrow[2][4], lrow[2][4];
#pragma unroll
  for (int mt = 0; mt < 2; ++mt)
#pragma unroll
    for (int r = 0; r < 4; ++r) {
      mrow[mt][r] = -1e30f;
      lrow[mt][r] = 0.f;
    }

  const int stok = tid >> 2;
  const int sd = (tid & 3) * 16;
  const bf16_t* kp0 = base + (size_t)stok * C3 + C + h * 64 + sd;
  const bf16_t* vp0 = kp0 + C;

  for (int j0 = 0; j0 <= Q0 + 64; j0 += 64) {
    __syncthreads();  // protect Ks/Vt rewrite vs previous reads
    {
      const bf16_t* kp = kp0 + (size_t)j0 * C3;
      *(bf16x8*)&Ks[stok * 72 + sd] = *(const bf16x8*)kp;
      *(bf16x8*)&Ks[stok * 72 + sd + 8] = *(const bf16x8*)(kp + 8);
      const bf16_t* vp = vp0 + (size_t)j0 * C3;
      bf16x8 v0 = *(const bf16x8*)vp;
      bf16x8 v1 = *(const bf16x8*)(vp + 8);
#pragma unroll
      for (int e = 0; e < 8; ++e) {
        Vt[(sd + e) * 72 + stok] = v0[e];
        Vt[(sd + 8 + e) * 72 + stok] = v1[e];
      }
    }
    __syncthreads();

    if (Q0 + wave * 32 + 31 >= j0) {  // wave-uniform: skip fully-masked wave
#pragma unroll
      for (int mt = 0; mt < 2; ++mt) {
        if (Q0 + wave * 32 + mt * 16 + 15 < j0) continue;  // masked m-tile
        const int qrow = Q0 + wave * 32 + mt * 16 + quad * 4;

        float Sv[4][4];
#pragma unroll
        for (int nt = 0; nt < 4; ++nt) {
          f32x4 s = {};
#pragma unroll
          for (int s2 = 0; s2 < 2; ++s2) {
            bf16x8 kf =
                *(const bf16x8*)&Ks[(nt * 16 + l16) * 72 + s2 * 32 + quad * 8];
            s = MFMA16(qf[mt][s2], kf, s);
          }
          const int key = j0 + nt * 16 + l16;
#pragma unroll
          for (int r = 0; r < 4; ++r)
            Sv[nt][r] = (key > qrow + r) ? -1e30f : s[r];
        }

        float alpha[4], mnew[4];
#pragma unroll
        for (int r = 0; r < 4; ++r) {
          float v = fmaxf(fmaxf(Sv[0][r], Sv[1][r]), fmaxf(Sv[2][r], Sv[3][r]));
#pragma unroll
          for (int off = 1; off < 16; off <<= 1)
            v = fmaxf(v, __shfl_xor(v, off, 16));
          mnew[r] = fmaxf(mrow[mt][r], v);
          alpha[r] = __expf(mrow[mt][r] - mnew[r]);
          mrow[mt][r] = mnew[r];
        }
#pragma unroll
        for (int r = 0; r < 4; ++r) {
          float rs = 0.f;
#pragma unroll
          for (int nt = 0; nt < 4; ++nt) {
            float p = __expf(Sv[nt][r] - mnew[r]);
            Sv[nt][r] = p;
            rs += p;
          }
#pragma unroll
          for (int off = 1; off < 16; off <<= 1) rs += __shfl_xor(rs, off, 16);
          lrow[mt][r] = lrow[mt][r] * alpha[r] + rs;
        }
#pragma unroll
        for (int dt = 0; dt < 4; ++dt)
#pragma unroll
          for (int r = 0; r < 4; ++r) Of[mt][dt][r] *= alpha[r];

        // P: C-layout regs -> LDS -> A-layout (wave-private; no barrier)
        bf16_t* pw = &Ps[wave * 16 * 72];
#pragma unroll
        for (int nt = 0; nt < 4; ++nt)
#pragma unroll
          for (int r = 0; r < 4; ++r)
            pw[(quad * 4 + r) * 72 + nt * 16 + l16] = (bf16_t)Sv[nt][r];

        bf16x8 pf0 = *(const bf16x8*)&pw[l16 * 72 + quad * 8];
        bf16x8 pf1 = *(const bf16x8*)&pw[l16 * 72 + 32 + quad * 8];
#pragma unroll
        for (int dt = 0; dt < 4; ++dt) {
          bf16x8 vf0 =
              *(const bf16x8*)&Vt[(dt * 16 + l16) * 72 + quad * 8];
          bf16x8 vf1 =
              *(const bf16x8*)&Vt[(dt * 16 + l16) * 72 + 32 + quad * 8];
          Of[mt][dt] = MFMA16(pf0, vf0, Of[mt][dt]);
          Of[mt][dt] = MFMA16(pf1, vf1, Of[mt][dt]);
        }
      }
    }
  }

  // epilogue: write O/l over this wave's own Q rows
#pragma unroll
  for (int mt = 0; mt < 2; ++mt) {
    const int t = Q0 + wave * 32 + mt * 16 + quad * 4;
#pragma unroll
    for (int r = 0; r < 4; ++r) {
      const float inv = 1.0f / lrow[mt][r];
      bf16_t* op = base + (size_t)(t + r) * C3 + h * 64 + l16;
#pragma unroll
      for (int dt = 0; dt < 4; ++dt)
        op[dt * 16] = (bf16_t)(Of[mt][dt][r] * inv);
    }
  }
}

// ---------------------------------------------------------------------------
// I/O contract (R8 probe): ALL inputs f32; output f32.
// ---------------------------------------------------------------------------
extern "C" void kernel_launch(void* const* d_in, const int* in_sizes, int n_in,
                              void* d_out, int out_size, void* d_ws,
                              size_t ws_size, hipStream_t stream) {
  constexpr int B = 4, T = 2048, C = 1024;
  constexpr int M = B * T;  // 8192

  const float* x = (const float*)d_in[0];
  const float* w_qkv = (const float*)d_in[1];
  const float* w_out = (const float*)d_in[2];
  const float* b_out = (const float*)d_in[3];
  for (int i = 0; i < n_in; ++i) {
    const long long s = in_sizes[i];
    if (s == (long long)M * C) x = (const float*)d_in[i];
    else if (s == (long long)3 * C * C) w_qkv = (const float*)d_in[i];
    else if (s == (long long)C * C) w_out = (const float*)d_in[i];
    else if (s == C) b_out = (const float*)d_in[i];
  }

  // bf16 copies of x and w_qkv live in d_out (32 MB): dead before the final
  // GEMM overwrites d_out. ws holds only qkv [M,3C] bf16 = 48 MB (proven).
  bf16_t* xb = (bf16_t*)d_out;                    // 16 MB
  bf16_t* wqb = xb + (size_t)M * C;               // 6 MB
  bf16_t* qkv = (bf16_t*)d_ws;                    // 48 MB

  cvt_f32_bf16<<<1024, 256, 0, stream>>>(x, xb, (long long)M * C);
  cvt_f32_bf16<<<512, 256, 0, stream>>>(w_qkv, wqb, 3LL * C * C);

  // fused QKV: [M,3C] = xb @ wqb^T
  gemm_async<false, bf16_t, false>
      <<<dim3(3 * C / 128, M / 128), 256, 0, stream>>>(
          xb, C, wqb, nullptr, qkv, 3 * C, M, 3 * C, C);

  // attention in place (Q slot of qkv)
  attn_mfma<<<dim3(T / 128, B * 16), 256, 0, stream>>>(qkv);

  // out = att @ w_out^T + b_out -> f32 d_out (overwrites xb/wqb, now dead)
  gemm_async<true, float, true><<<dim3(C / 128, M / 128), 256, 0, stream>>>(
      qkv, 3 * C, w_out, b_out, (float*)d_out, C, M, C, C);
}

// Round 11
// 331.187 us; speedup vs baseline: 1.7972x; 1.3093x over previous
//
#include <hip/hip_runtime.h>
#include <hip/hip_bf16.h>

typedef __bf16 bf16_t;
typedef __bf16 bf16x8 __attribute__((ext_vector_type(8)));
typedef float f32x4 __attribute__((ext_vector_type(4)));

#define MFMA16(a, b, c) __builtin_amdgcn_mfma_f32_16x16x32_bf16(a, b, c, 0, 0, 0)

// async 16B global->LDS (m97 pattern). lds ptr wave-uniform; lane writes
// ldsbase + lane*16.
__device__ __forceinline__ void gld16(const bf16_t* g, bf16_t* l) {
  __builtin_amdgcn_global_load_lds(
      (const __attribute__((address_space(1))) unsigned int*)(const void*)g,
      (__attribute__((address_space(3))) unsigned int*)(void*)l, 16, 0, 0);
}

// ---------------------------------------------------------------------------
// f32 -> bf16 elementwise convert (n multiple of 8)
// ---------------------------------------------------------------------------
__global__ __launch_bounds__(256) void cvt_f32_bf16(
    const float* __restrict__ src, bf16_t* __restrict__ dst, long long n) {
  long long i = ((long long)blockIdx.x * 256 + threadIdx.x) * 8;
  const long long stride = (long long)gridDim.x * 256 * 8;
  for (; i < n; i += stride) {
    f32x4 a = *(const f32x4*)(src + i);
    f32x4 b = *(const f32x4*)(src + i + 4);
    bf16x8 r;
#pragma unroll
    for (int e = 0; e < 4; ++e) {
      r[e] = (bf16_t)a[e];
      r[4 + e] = (bf16_t)b[e];
    }
    *(bf16x8*)(dst + i) = r;
  }
}

// ---------------------------------------------------------------------------
// GEMM: C[m][n] = sum_k A[m][k]*W[n][k] (+bias). A bf16 via global_load_lds.
// W: bf16 via global_load_lds (WF32=false) or f32 via cvt staging (true).
// 128x128 tile, 4 waves (2x2), 64x64/wave, BK=32. Layouts R5==R6 verified.
// ---------------------------------------------------------------------------
template <bool WF32, typename TC, bool BIAS>
__global__ __launch_bounds__(256, 2) void gemm_async(
    const bf16_t* __restrict__ A, int lda, const void* __restrict__ Wv,
    const float* __restrict__ bias, TC* __restrict__ C, int ldc,
    int M, int N, int K) {
  constexpr int BST = WF32 ? 40 : 32;
  __shared__ bf16_t As[128 * 32];   // unpadded: global_load_lds layout
  __shared__ bf16_t Bs[128 * BST];

  const int tid = threadIdx.x;
  const int i = tid & 63;
  const int w = tid >> 6;
  const int l16 = tid & 15;
  const int quad = (tid >> 4) & 3;
  const int wm = w & 1;
  const int wn = w >> 1;
  const int m0 = blockIdx.y * 128;
  const int n0 = blockIdx.x * 128;

  const bf16_t* ag = A + (size_t)(m0 + w * 32 + (i >> 2)) * lda + (i & 3) * 8;
  bf16_t* as0 = &As[(w * 32) * 32];
  bf16_t* as1 = &As[(w * 32 + 16) * 32];

  const bf16_t* bg = nullptr;
  bf16_t *bs0 = nullptr, *bs1 = nullptr;
  const float* wfg = nullptr;
  bf16_t* bsw = nullptr;
  if (!WF32) {
    bg = (const bf16_t*)Wv + (size_t)(n0 + w * 32 + (i >> 2)) * K + (i & 3) * 8;
    bs0 = &Bs[(w * 32) * 32];
    bs1 = &Bs[(w * 32 + 16) * 32];
  } else {
    const int srow = tid >> 1;
    const int scol = (tid & 1) * 16;
    wfg = (const float*)Wv + (size_t)(n0 + srow) * K + scol;
    bsw = &Bs[srow * BST + scol];
  }

  f32x4 acc[4][4] = {};

  for (int k0 = 0; k0 < K; k0 += 32) {
    __syncthreads();
    gld16(ag + k0, as0);
    gld16(ag + 16 * lda + k0, as1);
    if (!WF32) {
      gld16(bg + k0, bs0);
      gld16(bg + 16 * K + k0, bs1);
    } else {
      f32x4 a = *(const f32x4*)(wfg + k0);
      f32x4 b = *(const f32x4*)(wfg + k0 + 4);
      f32x4 c2 = *(const f32x4*)(wfg + k0 + 8);
      f32x4 d = *(const f32x4*)(wfg + k0 + 12);
      bf16x8 r0, r1;
#pragma unroll
      for (int e = 0; e < 4; ++e) {
        r0[e] = (bf16_t)a[e];
        r0[4 + e] = (bf16_t)b[e];
        r1[e] = (bf16_t)c2[e];
        r1[4 + e] = (bf16_t)d[e];
      }
      *(bf16x8*)(bsw) = r0;
      *(bf16x8*)(bsw + 8) = r1;
    }
    __syncthreads();

    bf16x8 af[4], bfr[4];
#pragma unroll
    for (int t = 0; t < 4; ++t) {
      af[t] = *(const bf16x8*)&As[(wm * 64 + t * 16 + l16) * 32 + quad * 8];
      bfr[t] = *(const bf16x8*)&Bs[(wn * 64 + t * 16 + l16) * BST + quad * 8];
    }
#pragma unroll
    for (int mi = 0; mi < 4; ++mi)
#pragma unroll
      for (int ni = 0; ni < 4; ++ni)
        acc[mi][ni] = MFMA16(af[mi], bfr[ni], acc[mi][ni]);
  }

#pragma unroll
  for (int ni = 0; ni < 4; ++ni) {
    const int col = n0 + wn * 64 + ni * 16 + l16;
    const float bv = BIAS ? bias[col] : 0.0f;
#pragma unroll
    for (int mi = 0; mi < 4; ++mi) {
      const int row = m0 + wm * 64 + mi * 16 + quad * 4;
#pragma unroll
      for (int r = 0; r < 4; ++r)
        C[(size_t)(row + r) * ldc + col] = (TC)(acc[mi][ni][r] + bv);
    }
  }
}

// ---------------------------------------------------------------------------
// Flash attention (causal), qkv interleaved [B*T, 3C] bf16 (q|k|v).
// Output overwrites the Q slot in place (R3-verified disjointness).
//
// Work-balanced: block p processes q-strips qt=p and qt=15-p sequentially ->
// every block does exactly 34 j-tiles (uniform). Grid (8, B*H) = 512 blocks
// of 512 threads (8 waves); 2 blocks/CU = 16 waves/CU, all busy to the end.
// Per strip (128 q-rows): wave w owns rows w*16..+15.
// Staging per tile: waves 0-3 stage K (b128, 2-way banks); waves 4-7 stage
// V transposed with token-major lanes (scalar stores hit all 32 banks,
// 2-way = free; fixes R10's 8-way conflict).
// Q pre-scaled by 1/8 (exact). Layouts R3==R4 verified on device.
// ---------------------------------------------------------------------------
__global__ __launch_bounds__(512, 4) void attn_mfma(bf16_t* __restrict__ qkv) {
  constexpr int T = 2048, C3 = 3072, C = 1024;
  __shared__ bf16_t Ks[64 * 72];      // [token][d], +8 pad
  __shared__ bf16_t Vt[64 * 72];      // [d][token], +8 pad
  __shared__ bf16_t Ps[8 * 16 * 72];  // per-wave P tile

  const int tid = threadIdx.x;
  const int wave = tid >> 6;        // 0..7
  const int lane = tid & 63;
  const int l16 = tid & 15;
  const int quad = (tid >> 4) & 3;
  const int p = blockIdx.x;         // 0..7 -> strips p and 15-p
  const int b = blockIdx.y >> 4;
  const int h = blockIdx.y & 15;
  bf16_t* base = qkv + (size_t)b * T * C3;

  // K staging map (waves 0-3): token = tid>>2 (0..63), 16 d's at (tid&3)*16
  const int kst = tid >> 2;
  const int ksd = (tid & 3) * 16;
  // V staging map (waves 4-7): token = lane, 16 d's at (wave-4)*16
  const int vtok = lane;
  const int vdg = (wave - 4) * 16;

  bf16_t* pw = &Ps[wave * 16 * 72];

  for (int s = 0; s < 2; ++s) {
    const int qt = (s == 0) ? p : 15 - p;
    const int Q0 = qt * 128;
    const int qlo = Q0 + wave * 16;

    // Q fragments, prescaled by 0.125 (power of 2: exact in bf16)
    bf16x8 qf[2];
    {
      const bf16_t* qp = base + (size_t)(qlo + l16) * C3 + h * 64 + quad * 8;
      bf16x8 a = *(const bf16x8*)qp;
      bf16x8 c = *(const bf16x8*)(qp + 32);
#pragma unroll
      for (int e = 0; e < 8; ++e) {
        a[e] = (bf16_t)((float)a[e] * 0.125f);
        c[e] = (bf16_t)((float)c[e] * 0.125f);
      }
      qf[0] = a;
      qf[1] = c;
    }

    f32x4 Of[4] = {};
    float mrow[4] = {-1e30f, -1e30f, -1e30f, -1e30f};
    float lrow[4] = {0.f, 0.f, 0.f, 0.f};

    for (int j0 = 0; j0 <= Q0 + 64; j0 += 64) {
      __syncthreads();  // protect Ks/Vt rewrite vs previous tile's reads
      if (wave < 4) {
        const bf16_t* kp = base + (size_t)(j0 + kst) * C3 + C + h * 64 + ksd;
        *(bf16x8*)&Ks[kst * 72 + ksd] = *(const bf16x8*)kp;
        *(bf16x8*)&Ks[kst * 72 + ksd + 8] = *(const bf16x8*)(kp + 8);
      } else {
        const bf16_t* vp =
            base + (size_t)(j0 + vtok) * C3 + 2 * C + h * 64 + vdg;
        bf16x8 v0 = *(const bf16x8*)vp;
        bf16x8 v1 = *(const bf16x8*)(vp + 8);
#pragma unroll
        for (int e = 0; e < 8; ++e) {
          Vt[(vdg + e) * 72 + vtok] = v0[e];
          Vt[(vdg + 8 + e) * 72 + vtok] = v1[e];
        }
      }
      __syncthreads();

      if (qlo + 15 < j0) continue;  // wave-uniform: fully-masked wave skips
      const int qrow = qlo + quad * 4;

      float Sv[4][4];
#pragma unroll
      for (int nt = 0; nt < 4; ++nt) {
        f32x4 sacc = {};
#pragma unroll
        for (int s2 = 0; s2 < 2; ++s2) {
          bf16x8 kf =
              *(const bf16x8*)&Ks[(nt * 16 + l16) * 72 + s2 * 32 + quad * 8];
          sacc = MFMA16(qf[s2], kf, sacc);
        }
        const int key = j0 + nt * 16 + l16;
#pragma unroll
        for (int r = 0; r < 4; ++r)
          Sv[nt][r] = (key > qrow + r) ? -1e30f : sacc[r];
      }

      float alpha[4], mnew[4];
#pragma unroll
      for (int r = 0; r < 4; ++r) {
        float v = fmaxf(fmaxf(Sv[0][r], Sv[1][r]), fmaxf(Sv[2][r], Sv[3][r]));
#pragma unroll
        for (int off = 1; off < 16; off <<= 1)
          v = fmaxf(v, __shfl_xor(v, off, 16));
        mnew[r] = fmaxf(mrow[r], v);
        alpha[r] = __expf(mrow[r] - mnew[r]);
        mrow[r] = mnew[r];
      }
#pragma unroll
      for (int r = 0; r < 4; ++r) {
        float rs = 0.f;
#pragma unroll
        for (int nt = 0; nt < 4; ++nt) {
          float pr = __expf(Sv[nt][r] - mnew[r]);
          Sv[nt][r] = pr;
          rs += pr;
        }
#pragma unroll
        for (int off = 1; off < 16; off <<= 1) rs += __shfl_xor(rs, off, 16);
        lrow[r] = lrow[r] * alpha[r] + rs;
      }
#pragma unroll
      for (int dt = 0; dt < 4; ++dt)
#pragma unroll
        for (int r = 0; r < 4; ++r) Of[dt][r] *= alpha[r];

      // P: C-layout regs -> LDS -> A-layout (wave-private; no barrier)
#pragma unroll
      for (int nt = 0; nt < 4; ++nt)
#pragma unroll
        for (int r = 0; r < 4; ++r)
          pw[(quad * 4 + r) * 72 + nt * 16 + l16] = (bf16_t)Sv[nt][r];

      bf16x8 pf0 = *(const bf16x8*)&pw[l16 * 72 + quad * 8];
      bf16x8 pf1 = *(const bf16x8*)&pw[l16 * 72 + 32 + quad * 8];
#pragma unroll
      for (int dt = 0; dt < 4; ++dt) {
        bf16x8 vf0 = *(const bf16x8*)&Vt[(dt * 16 + l16) * 72 + quad * 8];
        bf16x8 vf1 = *(const bf16x8*)&Vt[(dt * 16 + l16) * 72 + 32 + quad * 8];
        Of[dt] = MFMA16(pf0, vf0, Of[dt]);
        Of[dt] = MFMA16(pf1, vf1, Of[dt]);
      }
    }

    // epilogue: write O/l over this wave's own Q rows
    const int t = Q0 + wave * 16 + quad * 4;
#pragma unroll
    for (int r = 0; r < 4; ++r) {
      const float inv = 1.0f / lrow[r];
      bf16_t* op = base + (size_t)(t + r) * C3 + h * 64 + l16;
#pragma unroll
      for (int dt = 0; dt < 4; ++dt)
        op[dt * 16] = (bf16_t)(Of[dt][r] * inv);
    }
  }
}

// ---------------------------------------------------------------------------
// I/O contract (R8 probe): ALL inputs f32; output f32.
// ---------------------------------------------------------------------------
extern "C" void kernel_launch(void* const* d_in, const int* in_sizes, int n_in,
                              void* d_out, int out_size, void* d_ws,
                              size_t ws_size, hipStream_t stream) {
  constexpr int B = 4, T = 2048, C = 1024;
  constexpr int M = B * T;  // 8192

  const float* x = (const float*)d_in[0];
  const float* w_qkv = (const float*)d_in[1];
  const float* w_out = (const float*)d_in[2];
  const float* b_out = (const float*)d_in[3];
  for (int i = 0; i < n_in; ++i) {
    const long long s = in_sizes[i];
    if (s == (long long)M * C) x = (const float*)d_in[i];
    else if (s == (long long)3 * C * C) w_qkv = (const float*)d_in[i];
    else if (s == (long long)C * C) w_out = (const float*)d_in[i];
    else if (s == C) b_out = (const float*)d_in[i];
  }

  // bf16 copies of x and w_qkv live in d_out (32 MB): dead before the final
  // GEMM overwrites d_out. ws holds qkv [M,3C] bf16 = 48 MB (proven safe).
  bf16_t* xb = (bf16_t*)d_out;                    // 16 MB
  bf16_t* wqb = xb + (size_t)M * C;               // 6 MB
  bf16_t* qkv = (bf16_t*)d_ws;                    // 48 MB

  cvt_f32_bf16<<<1024, 256, 0, stream>>>(x, xb, (long long)M * C);
  cvt_f32_bf16<<<512, 256, 0, stream>>>(w_qkv, wqb, 3LL * C * C);

  // fused QKV: [M,3C] = xb @ wqb^T
  gemm_async<false, bf16_t, false>
      <<<dim3(3 * C / 128, M / 128), 256, 0, stream>>>(
          xb, C, wqb, nullptr, qkv, 3 * C, M, 3 * C, C);

  // attention in place (Q slot of qkv); work-balanced pairing grid
  attn_mfma<<<dim3(8, B * 16), 512, 0, stream>>>(qkv);

  // out = att @ w_out^T + b_out -> f32 d_out (overwrites xb/wqb, now dead)
  gemm_async<true, float, true><<<dim3(C / 128, M / 128), 256, 0, stream>>>(
      qkv, 3 * C, w_out, b_out, (float*)d_out, C, M, C, C);
}